// Round 2
// baseline (837.558 us; speedup 1.0000x reference)
//
#include <hip/hip_runtime.h>
#include <cstdint>
#include <cstddef>

// SAGE 3-layer GNN, MI355X gfx950 — round 5:
//  * aggregate: 2-edges-per-instruction (32 lanes x 16B each) + 8-edge unroll
//    -> 4x uint4 loads in flight per wave (was 2x uint2). Half-combine by shfl.
//  * GEMM: full 256-col tile, W-half resident in 128KB LDS -> A read ONCE.
//  * count_edges + convert_x + 6 transposes fused into one segmented kernel.

#define N_NODES 100000
#define N_EDGES 1600000

#define SCAN_BLOCKS 256
#define SCAN_T 256
#define FILL_PASSES 4

typedef unsigned short ushort;
typedef unsigned int uint;
typedef __attribute__((ext_vector_type(8))) short short8;
typedef __attribute__((ext_vector_type(4))) float floatx4;

#define AS1 __attribute__((address_space(1)))
#define AS3 __attribute__((address_space(3)))

__device__ __forceinline__ float bf2f(ushort h) {
    union { uint u; float f; } c; c.u = ((uint)h) << 16; return c.f;
}
__device__ __forceinline__ ushort f2bf(float f) {
    union { float f; uint u; } c; c.f = f;
    uint u = c.u;
    return (ushort)((u + 0x7FFFu + ((u >> 16) & 1u)) >> 16);  // RTNE
}

// ---------------- fused prep: count_edges + convert_x + 6 W transposes ----

#define N4X (N_NODES * 128 / 4)

__global__ void prep_all(
    const int* __restrict__ dst, int* __restrict__ cnt,
    const float* __restrict__ x, ushort* __restrict__ xb,
    const float* __restrict__ Wl0, ushort* __restrict__ Wl0t,
    const float* __restrict__ Wr0, ushort* __restrict__ Wr0t,
    const float* __restrict__ Wl1, ushort* __restrict__ Wl1t,
    const float* __restrict__ Wr1, ushort* __restrict__ Wr1t,
    const float* __restrict__ Wl2, ushort* __restrict__ Wl2t,
    const float* __restrict__ Wr2, ushort* __restrict__ Wr2t)
{
    int i = blockIdx.x * blockDim.x + threadIdx.x;
    if (i < N_EDGES) { atomicAdd(&cnt[dst[i]], 1); return; }
    i -= N_EDGES;
    if (i < N4X) {
        float4 v = *(const float4*)&x[(size_t)i * 4];
        ushort4 o;
        o.x = f2bf(v.x); o.y = f2bf(v.y); o.z = f2bf(v.z); o.w = f2bf(v.w);
        *(ushort4*)&xb[(size_t)i * 4] = o;
        return;
    }
    i -= N4X;
    // transposes: Wt[n*K + k] = W[k*256 + n]
    if (i < 32768) { Wl0t[i] = f2bf(Wl0[(i & 127) * 256 + (i >> 7)]); return; }
    i -= 32768;
    if (i < 32768) { Wr0t[i] = f2bf(Wr0[(i & 127) * 256 + (i >> 7)]); return; }
    i -= 32768;
    if (i < 65536) { Wl1t[i] = f2bf(Wl1[(i & 255) * 256 + (i >> 8)]); return; }
    i -= 65536;
    if (i < 65536) { Wr1t[i] = f2bf(Wr1[(i & 255) * 256 + (i >> 8)]); return; }
    i -= 65536;
    if (i < 65536) { Wl2t[i] = f2bf(Wl2[(i & 255) * 256 + (i >> 8)]); return; }
    i -= 65536;
    if (i < 65536) { Wr2t[i] = f2bf(Wr2[(i & 255) * 256 + (i >> 8)]); return; }
}

// ---------------- CSR scan ----------------

__global__ __launch_bounds__(SCAN_T) void scan_partial(
    const int* __restrict__ cnt, int* __restrict__ bsum, int n)
{
    int chunk = (n + SCAN_BLOCKS - 1) / SCAN_BLOCKS;
    int beg = blockIdx.x * chunk;
    int end = beg + chunk; if (end > n) end = n;
    int t = threadIdx.x;
    int s = 0;
    for (int i = beg + t; i < end; i += SCAN_T) s += cnt[i];
    __shared__ int sh[SCAN_T];
    sh[t] = s;
    __syncthreads();
    for (int off = SCAN_T / 2; off > 0; off >>= 1) {
        if (t < off) sh[t] += sh[t + off];
        __syncthreads();
    }
    if (t == 0) bsum[blockIdx.x] = sh[0];
}

__global__ __launch_bounds__(SCAN_T) void scan_block_sums(int* __restrict__ bsum) {
    int t = threadIdx.x;
    __shared__ int sh[SCAN_T];
    int v = bsum[t];
    sh[t] = v;
    __syncthreads();
    for (int off = 1; off < SCAN_T; off <<= 1) {
        int u = (t >= off) ? sh[t - off] : 0;
        __syncthreads();
        sh[t] += u;
        __syncthreads();
    }
    bsum[t] = sh[t] - v;  // exclusive
}

__global__ __launch_bounds__(SCAN_T) void scan_fill(
    int* __restrict__ cnt, const int* __restrict__ bsum,
    int* __restrict__ row_ptr, int n)
{
    int chunk = (n + SCAN_BLOCKS - 1) / SCAN_BLOCKS;
    int beg = blockIdx.x * chunk;
    int end = beg + chunk; if (end > n) end = n;
    int t = threadIdx.x;
    int per = (chunk + SCAN_T - 1) / SCAN_T;
    int tb = beg + t * per;
    int te = tb + per; if (te > end) te = end;
    int s = 0;
    for (int i = tb; i < te; ++i) s += cnt[i];
    __shared__ int sh[SCAN_T];
    sh[t] = s;
    __syncthreads();
    for (int off = 1; off < SCAN_T; off <<= 1) {
        int u = (t >= off) ? sh[t - off] : 0;
        __syncthreads();
        sh[t] += u;
        __syncthreads();
    }
    int running = bsum[blockIdx.x] + sh[t] - s;
    for (int i = tb; i < te; ++i) {
        int c = cnt[i];
        row_ptr[i] = running;
        cnt[i] = running;  // becomes fill cursor
        running += c;
    }
    if (blockIdx.x == 0 && t == 0) row_ptr[n] = N_EDGES;
}

// 4 dst-range passes: per-pass dirty col_idx region (~1.6MB) stays L2-resident.
__global__ void fill_csr(const int* __restrict__ src, const int* __restrict__ dst,
                         int* __restrict__ cursor, int* __restrict__ col_idx) {
    int i = blockIdx.x * blockDim.x + threadIdx.x;
    if (i >= N_EDGES) return;
    int lo = (int)blockIdx.y * (N_NODES / FILL_PASSES);
    int hi = lo + (N_NODES / FILL_PASSES);
    int d = dst[i];
    if (d >= lo && d < hi) {
        int p = atomicAdd(&cursor[d], 1);
        col_idx[p] = src[i];
    }
}

// ---------------- mean aggregation ----------------
// 1 wave per node. Lanes 0-31 handle even edge of a pair, 32-63 the odd edge;
// each lane loads 16B (F=256) / 8B (F=128) of the row. 8-edge unroll -> 4
// outstanding gathers per wave. Halves combined by one shfl at the end.
__global__ __launch_bounds__(64) void aggregate_bf16(
    const ushort* __restrict__ xb, const int* __restrict__ row_ptr,
    const int* __restrict__ col_idx, ushort* __restrict__ outb, int F)
{
    int node = blockIdx.x;
    int lane = threadIdx.x;
    int half = lane >> 5, li = lane & 31;
    int b = row_ptr[node], e = row_ptr[node + 1];
    float d = (float)(e - b); if (d < 1.f) d = 1.f;
    float inv = 1.f / d;

    if (F == 256) {
        float a[8];
#pragma unroll
        for (int j = 0; j < 8; ++j) a[j] = 0.f;
        const int c = li * 8;  // ushort offset within row (16B per lane)
        int i = b;
        for (; i + 7 < e; i += 8) {
            int s0 = col_idx[i + half];
            int s1 = col_idx[i + 2 + half];
            int s2 = col_idx[i + 4 + half];
            int s3 = col_idx[i + 6 + half];
            uint4 v0 = *(const uint4*)&xb[(size_t)s0 * 256 + c];
            uint4 v1 = *(const uint4*)&xb[(size_t)s1 * 256 + c];
            uint4 v2 = *(const uint4*)&xb[(size_t)s2 * 256 + c];
            uint4 v3 = *(const uint4*)&xb[(size_t)s3 * 256 + c];
#define ACC4(v) \
            a[0] += bf2f((ushort)(v.x & 0xffff)); a[1] += bf2f((ushort)(v.x >> 16)); \
            a[2] += bf2f((ushort)(v.y & 0xffff)); a[3] += bf2f((ushort)(v.y >> 16)); \
            a[4] += bf2f((ushort)(v.z & 0xffff)); a[5] += bf2f((ushort)(v.z >> 16)); \
            a[6] += bf2f((ushort)(v.w & 0xffff)); a[7] += bf2f((ushort)(v.w >> 16));
            ACC4(v0) ACC4(v1) ACC4(v2) ACC4(v3)
        }
        for (; i + 1 < e; i += 2) {
            int s0 = col_idx[i + half];
            uint4 v0 = *(const uint4*)&xb[(size_t)s0 * 256 + c];
            ACC4(v0)
        }
        if (i < e && half == 0) {
            int s0 = col_idx[i];
            uint4 v0 = *(const uint4*)&xb[(size_t)s0 * 256 + c];
            ACC4(v0)
        }
#undef ACC4
#pragma unroll
        for (int j = 0; j < 8; ++j) a[j] += __shfl(a[j], li + 32);
        if (half == 0) {
            short8 o;
#pragma unroll
            for (int j = 0; j < 8; ++j) o[j] = (short)f2bf(a[j] * inv);
            *(short8*)&outb[(size_t)node * 256 + c] = o;
        }
    } else {
        float a[4];
#pragma unroll
        for (int j = 0; j < 4; ++j) a[j] = 0.f;
        const int c = li * 4;  // 8B per lane
        int i = b;
        for (; i + 7 < e; i += 8) {
            int s0 = col_idx[i + half];
            int s1 = col_idx[i + 2 + half];
            int s2 = col_idx[i + 4 + half];
            int s3 = col_idx[i + 6 + half];
            uint2 v0 = *(const uint2*)&xb[(size_t)s0 * 128 + c];
            uint2 v1 = *(const uint2*)&xb[(size_t)s1 * 128 + c];
            uint2 v2 = *(const uint2*)&xb[(size_t)s2 * 128 + c];
            uint2 v3 = *(const uint2*)&xb[(size_t)s3 * 128 + c];
#define ACC2(v) \
            a[0] += bf2f((ushort)(v.x & 0xffff)); a[1] += bf2f((ushort)(v.x >> 16)); \
            a[2] += bf2f((ushort)(v.y & 0xffff)); a[3] += bf2f((ushort)(v.y >> 16));
            ACC2(v0) ACC2(v1) ACC2(v2) ACC2(v3)
        }
        for (; i + 1 < e; i += 2) {
            int s0 = col_idx[i + half];
            uint2 v0 = *(const uint2*)&xb[(size_t)s0 * 128 + c];
            ACC2(v0)
        }
        if (i < e && half == 0) {
            int s0 = col_idx[i];
            uint2 v0 = *(const uint2*)&xb[(size_t)s0 * 128 + c];
            ACC2(v0)
        }
#undef ACC2
#pragma unroll
        for (int j = 0; j < 4; ++j) a[j] += __shfl(a[j], li + 32);
        if (half == 0) {
            ushort4 o;
            o.x = f2bf(a[0] * inv); o.y = f2bf(a[1] * inv);
            o.z = f2bf(a[2] * inv); o.w = f2bf(a[3] * inv);
            *(ushort4*)&outb[(size_t)node * 128 + c] = o;
        }
    }
}

// ---------------- W-resident dual MFMA GEMM, full 256-col tile ----------------
// C[M,256] = relu?( A1[M,K]@W1 + A2[M,K]@W2 + bias ).
// 512 thr (8 waves), tile 256 rows x 256 cols. W-half for one mm phase lives
// in 128KB LDS (loaded once per phase); A-frags straight global->VGPR
// (16 rows x 64B per wave, coalesced). K-loop: no barriers, no vmcnt drains.
// A is read exactly ONCE per GEMM (was twice with the 128-col split).
__global__ __launch_bounds__(512, 1) void gemm_wres(
    const ushort* __restrict__ A1, const ushort* __restrict__ W1t,
    const ushort* __restrict__ A2, const ushort* __restrict__ W2t,
    const float* __restrict__ bias, ushort* __restrict__ out_bf,
    float* __restrict__ out_f32, int M, int K, int relu)
{
    __shared__ __align__(16) ushort Wl[32 * 256 * 8];  // 128KB, K<=256
    int tid = threadIdx.x;
    int w = tid >> 6, lane = tid & 63;
    int m_ = lane & 15, koq = lane >> 4;
    int row0 = blockIdx.x * 256;
    int KQ = K >> 3;               // 16B k-chunks per W column
    int nj = (KQ * 256) >> 9;      // staging rounds (slots/512)
    int nk = K >> 5;               // MFMA K-steps per mm

    floatx4 acc[2][16];
#pragma unroll
    for (int i = 0; i < 2; ++i)
#pragma unroll
        for (int f = 0; f < 16; ++f) acc[i][f] = (floatx4){0.f, 0.f, 0.f, 0.f};

    int ra = row0 + w * 32 + m_;      if (ra > M - 1) ra = M - 1;
    int rb = row0 + w * 32 + 16 + m_; if (rb > M - 1) rb = M - 1;

    for (int mm = 0; mm < 2; ++mm) {
        const ushort* __restrict__ A  = mm ? A2 : A1;
        const ushort* __restrict__ Wt = mm ? W2t : W1t;
        if (mm) __syncthreads();  // all waves done reading Wl before overwrite
        // stage W-half: slot s = q*256+col -> LDS byte s*16 (linear),
        // source Wt[col*K + q*8]; dst is wave-uniform base + lane*16.
        for (int j = 0; j < nj; ++j) {
            int s = j * 512 + tid;
            int q = s >> 8, col = s & 255;
            __builtin_amdgcn_global_load_lds(
                (const AS1 uint*)&Wt[(size_t)col * K + q * 8],
                (AS3 uint*)&Wl[(size_t)(j * 512 + w * 64) * 8], 16, 0, 0);
        }
        __syncthreads();

        const ushort* __restrict__ Aa = &A[(size_t)ra * K + koq * 8];
        const ushort* __restrict__ Ab = &A[(size_t)rb * K + koq * 8];

        short8 a0 = *(const short8*)&Aa[0];
        short8 a1 = *(const short8*)&Ab[0];
        for (int kk = 0; kk < nk; ++kk) {
            short8 n0, n1;
            if (kk + 1 < nk) {            // prefetch next A-frags
                n0 = *(const short8*)&Aa[(kk + 1) * 32];
                n1 = *(const short8*)&Ab[(kk + 1) * 32];
            }
            const ushort* bbase = &Wl[(size_t)((kk * 4 + koq) * 256 + m_) * 8];
#pragma unroll
            for (int fc = 0; fc < 16; ++fc) {
                short8 b = *(const short8*)&bbase[fc * 128];  // fc*16 slots * 8
                acc[0][fc] = __builtin_amdgcn_mfma_f32_16x16x32_bf16(a0, b, acc[0][fc], 0, 0, 0);
                acc[1][fc] = __builtin_amdgcn_mfma_f32_16x16x32_bf16(a1, b, acc[1][fc], 0, 0, 0);
            }
            a0 = n0; a1 = n1;
        }
    }

    // epilogue: frag C layout col = m_, row = koq*4 + r
#pragma unroll
    for (int m2 = 0; m2 < 2; ++m2) {
#pragma unroll
        for (int fc = 0; fc < 16; ++fc) {
            int col = fc * 16 + m_;
            float bv = bias[col];
#pragma unroll
            for (int r = 0; r < 4; ++r) {
                int row = row0 + w * 32 + m2 * 16 + koq * 4 + r;
                if (row >= M) continue;
                float v = acc[m2][fc][r] + bv;
                if (relu) v = fmaxf(v, 0.f);
                if (out_f32) out_f32[(size_t)row * 256 + col] = v;
                else         out_bf [(size_t)row * 256 + col] = f2bf(v);
            }
        }
    }
}

// ---------------- launch ----------------

extern "C" void kernel_launch(void* const* d_in, const int* in_sizes, int n_in,
                              void* d_out, int out_size, void* d_ws, size_t ws_size,
                              hipStream_t stream) {
    const float* x    = (const float*)d_in[0];
    const float* W_l0 = (const float*)d_in[1];
    const float* b_l0 = (const float*)d_in[2];
    const float* W_r0 = (const float*)d_in[3];
    const float* W_l1 = (const float*)d_in[4];
    const float* b_l1 = (const float*)d_in[5];
    const float* W_r1 = (const float*)d_in[6];
    const float* W_l2 = (const float*)d_in[7];
    const float* b_l2 = (const float*)d_in[8];
    const float* W_r2 = (const float*)d_in[9];
    const int* esrc   = (const int*)d_in[10];
    const int* edst   = (const int*)d_in[11];
    float* out = (float*)d_out;

    size_t off = 0;
    char* ws = (char*)d_ws;
    auto take = [&](size_t bytes) -> void* {
        void* p = ws + off;
        off += (bytes + 255) & ~(size_t)255;
        return p;
    };
    int*    cnt     = (int*)take((size_t)N_NODES * 4);
    int*    row_ptr = (int*)take((size_t)(N_NODES + 1) * 4);
    int*    col_idx = (int*)take((size_t)N_EDGES * 4);
    int*    bsum    = (int*)take((size_t)SCAN_BLOCKS * 4);
    ushort* xb      = (ushort*)take((size_t)N_NODES * 128 * 2);
    ushort* Wl0t    = (ushort*)take((size_t)256 * 128 * 2);
    ushort* Wr0t    = (ushort*)take((size_t)256 * 128 * 2);
    ushort* Wl1t    = (ushort*)take((size_t)256 * 256 * 2);
    ushort* Wr1t    = (ushort*)take((size_t)256 * 256 * 2);
    ushort* Wl2t    = (ushort*)take((size_t)256 * 256 * 2);
    ushort* Wr2t    = (ushort*)take((size_t)256 * 256 * 2);
    ushort* aggrb   = (ushort*)take((size_t)N_NODES * 256 * 2);
    ushort* ha      = (ushort*)take((size_t)N_NODES * 256 * 2);
    ushort* hb      = (ushort*)take((size_t)N_NODES * 256 * 2);
    (void)ws_size; (void)in_sizes; (void)n_in; (void)out_size;

    // prep: zero cnt, then fused count+convert+transposes
    hipMemsetAsync(cnt, 0, (size_t)N_NODES * 4, stream);
    int total_prep = N_EDGES + N4X + 2 * 32768 + 4 * 65536;
    prep_all<<<(total_prep + 255) / 256, 256, 0, stream>>>(
        edst, cnt, x, xb,
        W_l0, Wl0t, W_r0, Wr0t, W_l1, Wl1t, W_r1, Wr1t, W_l2, Wl2t, W_r2, Wr2t);

    // CSR scan + fill
    scan_partial<<<SCAN_BLOCKS, SCAN_T, 0, stream>>>(cnt, bsum, N_NODES);
    scan_block_sums<<<1, SCAN_T, 0, stream>>>(bsum);
    scan_fill<<<SCAN_BLOCKS, SCAN_T, 0, stream>>>(cnt, bsum, row_ptr, N_NODES);
    int eb = (N_EDGES + 255) / 256;
    fill_csr<<<dim3(eb, FILL_PASSES), 256, 0, stream>>>(esrc, edst, cnt, col_idx);

    dim3 ggrid((N_NODES + 255) / 256, 1);

    // layer 0: 128 -> 256, relu
    aggregate_bf16<<<N_NODES, 64, 0, stream>>>(xb, row_ptr, col_idx, aggrb, 128);
    gemm_wres<<<ggrid, 512, 0, stream>>>(aggrb, Wl0t, xb, Wr0t, b_l0,
                                         ha, nullptr, N_NODES, 128, 1);
    // layer 1: 256 -> 256, relu
    aggregate_bf16<<<N_NODES, 64, 0, stream>>>(ha, row_ptr, col_idx, aggrb, 256);
    gemm_wres<<<ggrid, 512, 0, stream>>>(aggrb, Wl1t, ha, Wr1t, b_l1,
                                         hb, nullptr, N_NODES, 256, 1);
    // layer 2: 256 -> 256, no relu, fp32 out
    aggregate_bf16<<<N_NODES, 64, 0, stream>>>(hb, row_ptr, col_idx, aggrb, 256);
    gemm_wres<<<ggrid, 512, 0, stream>>>(aggrb, Wl2t, hb, Wr2t, b_l2,
                                         nullptr, out, N_NODES, 256, 0);
}